// Round 11
// baseline (71.039 us; speedup 1.0000x reference)
//
#include <hip/hip_runtime.h>
#include <stdint.h>

typedef unsigned short u16;
typedef unsigned int   u32;
typedef __attribute__((ext_vector_type(8))) __bf16 bf16x8;
typedef __attribute__((ext_vector_type(4))) float  f32x4;
typedef __attribute__((ext_vector_type(2))) float  f32x2;
typedef __attribute__((ext_vector_type(4))) u32    u32x4;
typedef __attribute__((ext_vector_type(2))) u32    u32x2;

#define QSCALE 0.18033688011112042f   // log2(e) / sqrt(64)

__device__ __forceinline__ u16 f2bf(float x) {
  u32 u = __builtin_bit_cast(u32, x);
  u = (u + 0x7FFFu + ((u >> 16) & 1u)) >> 16;
  return (u16)u;
}

__device__ __forceinline__ u32 cvt_pk_bf16(float lo, float hi) {
  u32 r;
  asm("v_cvt_pk_bf16_f32 %0, %1, %2" : "=v"(r) : "v"(lo), "v"(hi));
  return r;
}

// ---------------------------------------------------------------------------
// Kernel 1: qkv = maxpool2(conv1x1(memory, W_qkv)) + b_qkv  — MFMA, 8 waves.
// ALSO folds W_out into V:  V' = W_out @ V^T  (64x64 GEMM on block-local V).
// outputs: Q [4][4096][64] bf16 (pre-scaled), K [4][4096][64] bf16,
//          V' [4][64][4096] bf16. Also zeroes the BN stats buffer.
// grid (64 oy, 4 b) x 512 threads
// ---------------------------------------------------------------------------
__global__ __launch_bounds__(512) void k_qkvpool(
    const float* __restrict__ mem, const float* __restrict__ Wqkv,
    const float* __restrict__ bqkv, const float* __restrict__ Wout,
    u16* __restrict__ Q, u16* __restrict__ K, u16* __restrict__ V,
    float* __restrict__ stats)
{
  const int oy = blockIdx.x, b = blockIdx.y, t = threadIdx.x;
  const int w = t >> 6, l4 = t & 15, lh = (t >> 4) & 3;
  const int wq = w & 3, wp = w >> 2;

  if (oy == 0 && b == 0 && t < 128) stats[t] = 0.f;

  __shared__ __align__(16) u16 lds[49152];      // 96 KB
  u16* mlds  = lds;           // [px 0..255][c] bf16, XOR-swizzled rows
  u16* wlds  = lds + 16384;   // [oc 0..191][c] bf16, swizzled
  u16* qlds  = lds + 28672;   // [ox][oc]
  u16* klds  = lds + 32768;   // [ox][oc-64]
  u16* vldsT = lds + 36864;   // [ox][vch] bf16, swizzled  (GEMM B operand)
  u16* wolds = lds + 40960;   // [oc 0..63][c] W_out bf16, swizzled
  u16* vplds = lds + 45056;   // [oc][ox]  V' output

  float bias[3][4];
  #pragma unroll
  for (int j = 0; j < 3; ++j)
    #pragma unroll
    for (int r = 0; r < 4; ++r) {
      int oc = wq * 48 + 16 * j + lh * 4 + r;
      float bv = bqkv[oc];
      bias[j][r] = (oc < 64) ? bv * QSCALE : bv;
    }

  { // stage mem rows (2oy, 2oy+1) -> bf16 LDS [px][c], swizzled
    const float* src = mem + ((size_t)b * 64) * 16384 + 2 * oy * 128;
    #pragma unroll
    for (int i = 0; i < 8; ++i) {
      int g = t + 512 * i;                 // 4-channel pack id, 0..4095
      int px = g & 255, c0 = (g >> 8) * 4;
      float f0 = src[(size_t)(c0 + 0) * 16384 + px];
      float f1 = src[(size_t)(c0 + 1) * 16384 + px];
      float f2 = src[(size_t)(c0 + 2) * 16384 + px];
      float f3 = src[(size_t)(c0 + 3) * 16384 + px];
      u32x2 pk;
      pk[0] = (u32)f2bf(f0) | ((u32)f2bf(f1) << 16);
      pk[1] = (u32)f2bf(f2) | ((u32)f2bf(f3) << 16);
      *(u32x2*)(mlds + px * 64 + (((c0 * 2) ^ ((px & 7) << 4)) >> 1)) = pk;
    }
  }
  { // stage W_qkv -> bf16 LDS [oc][c], swizzled
    #pragma unroll
    for (int i = 0; i < 6; ++i) {
      int g = t + 512 * i;                 // 0..3071
      int oc = g >> 4, c0 = (g & 15) * 4;
      f32x4 wv = *(const f32x4*)(Wqkv + oc * 64 + c0);
      u32x2 pk;
      pk[0] = (u32)f2bf(wv[0]) | ((u32)f2bf(wv[1]) << 16);
      pk[1] = (u32)f2bf(wv[2]) | ((u32)f2bf(wv[3]) << 16);
      *(u32x2*)(wlds + oc * 64 + (((c0 * 2) ^ ((oc & 7) << 4)) >> 1)) = pk;
    }
  }
  { // stage W_out -> bf16 LDS [oc][c], swizzled
    #pragma unroll
    for (int i = 0; i < 2; ++i) {
      int g = t + 512 * i;                 // 0..1023
      int oc = g >> 4, c0 = (g & 15) * 4;
      f32x4 wv = *(const f32x4*)(Wout + oc * 64 + c0);
      u32x2 pk;
      pk[0] = (u32)f2bf(wv[0]) | ((u32)f2bf(wv[1]) << 16);
      pk[1] = (u32)f2bf(wv[2]) | ((u32)f2bf(wv[3]) << 16);
      *(u32x2*)(wolds + oc * 64 + (((c0 * 2) ^ ((oc & 7) << 4)) >> 1)) = pk;
    }
  }
  __syncthreads();

  const int sw  = (l4 & 7) << 4;
  const int oF0 = ((lh * 16) ^ sw) >> 1;
  const int oF1 = ((64 + lh * 16) ^ sw) >> 1;
  bf16x8 af[3][2];
  #pragma unroll
  for (int j = 0; j < 3; ++j) {
    const u16* ar = wlds + (wq * 48 + 16 * j + l4) * 64;
    af[j][0] = *(const bf16x8*)(ar + oF0);
    af[j][1] = *(const bf16x8*)(ar + oF1);
  }

  // ---- main conv+pool loop: each wave handles 4 px-tile-pairs ----
  #pragma unroll 2
  for (int tpi = 0; tpi < 4; ++tpi) {
    const int tp = wp * 4 + tpi;
    const u16* br0 = mlds + (16 * tp + l4) * 64;
    const u16* br1 = mlds + (128 + 16 * tp + l4) * 64;
    bf16x8 b00 = *(const bf16x8*)(br0 + oF0);
    bf16x8 b01 = *(const bf16x8*)(br0 + oF1);
    bf16x8 b10 = *(const bf16x8*)(br1 + oF0);
    bf16x8 b11 = *(const bf16x8*)(br1 + oF1);
    const int ox = 8 * tp + (l4 >> 1);
    #pragma unroll
    for (int j = 0; j < 3; ++j) {
      f32x4 a0 = {0, 0, 0, 0}, a1 = {0, 0, 0, 0};
      a0 = __builtin_amdgcn_mfma_f32_16x16x32_bf16(af[j][0], b00, a0, 0, 0, 0);
      a0 = __builtin_amdgcn_mfma_f32_16x16x32_bf16(af[j][1], b01, a0, 0, 0, 0);
      a1 = __builtin_amdgcn_mfma_f32_16x16x32_bf16(af[j][0], b10, a1, 0, 0, 0);
      a1 = __builtin_amdgcn_mfma_f32_16x16x32_bf16(af[j][1], b11, a1, 0, 0, 0);
      const int ocj = wq * 48 + 16 * j;
      const float sc = (ocj < 64) ? QSCALE : 1.0f;
      #pragma unroll
      for (int r = 0; r < 4; ++r) {
        float m = fmaxf(a0[r], a1[r]);             // pool across rows
        m = fmaxf(m, __shfl_xor(m, 1, 64));        // pool across x pair
        u16 val = f2bf(m * sc + bias[j][r]);
        if ((l4 & 1) == 0) {
          int oc = ocj + lh * 4 + r;
          if (ocj < 64)       qlds[ox * 64 + oc]        = val;
          else if (ocj < 128) klds[ox * 64 + (oc - 64)] = val;
          else {
            int vch = oc - 128;   // [ox][vch], swizzled for GEMM B reads
            vldsT[ox * 64 + (((vch * 2) ^ ((ox & 7) << 4)) >> 1)] = val;
          }
        }
      }
    }
  }
  __syncthreads();

  // ---- V' = W_out @ V^T  (8 waves: oc-tile = wq*16, px-half = wp) ----
  {
    const u16* ar = wolds + (wq * 16 + l4) * 64;
    bf16x8 aw0 = *(const bf16x8*)(ar + oF0);
    bf16x8 aw1 = *(const bf16x8*)(ar + oF1);
    #pragma unroll
    for (int nti = 0; nti < 2; ++nti) {
      const int nt = wp * 2 + nti;
      const u16* brow = vldsT + (nt * 16 + l4) * 64;
      bf16x8 bw0 = *(const bf16x8*)(brow + oF0);
      bf16x8 bw1 = *(const bf16x8*)(brow + oF1);
      f32x4 u = {0, 0, 0, 0};
      u = __builtin_amdgcn_mfma_f32_16x16x32_bf16(aw0, bw0, u, 0, 0, 0);
      u = __builtin_amdgcn_mfma_f32_16x16x32_bf16(aw1, bw1, u, 0, 0, 0);
      #pragma unroll
      for (int r = 0; r < 4; ++r) {
        int oc = wq * 16 + lh * 4 + r;
        vplds[oc * 64 + nt * 16 + l4] = f2bf(u[r]);
      }
    }
  }
  __syncthreads();

  // ---- coalesced 16B copy-out ----
  {
    int r = t >> 3, e8 = (t & 7) * 8;
    size_t nb = (size_t)oy * 64;
    *(u32x4*)(Q + ((size_t)b * 4096 + nb + r) * 64 + e8) = *(const u32x4*)(qlds + r * 64 + e8);
    *(u32x4*)(K + ((size_t)b * 4096 + nb + r) * 64 + e8) = *(const u32x4*)(klds + r * 64 + e8);
    *(u32x4*)(V + ((size_t)b * 64 + r) * 4096 + nb + e8) = *(const u32x4*)(vplds + r * 64 + e8);
  }
}

// ---------------------------------------------------------------------------
// Kernel 2: flash attention — per-wave structure identical to round 6
// (swapped QK^T, P in registers, no-max softmax, 16 q-rows/wave), but the
// BLOCK is halved: 512 threads = 8 waves = 4 key-splits x 2 q-subtiles,
// 32 q-rows per block, LDS 69632 B -> TWO independent blocks per CU.
// Barrier stalls of the two blocks de-correlate (m114 wave-overlap), which
// is the occupancy cell rounds 6-10 never hit (16 waves/CU, 2 blocks).
// XCD mapping: batch b on XCD pair {2b,2b+1}; 128 q-blocks per batch.
// V is pre-multiplied by W_out: output IS U = W_out(PV)/L + b_out.
// grid 512 x 512 threads
// ---------------------------------------------------------------------------
__global__ __launch_bounds__(512) void k_attn(
    const u16* __restrict__ Q, const u16* __restrict__ K,
    const u16* __restrict__ V, const float* __restrict__ bo,
    float* __restrict__ Sa)
{
  const int bid = blockIdx.x, t = threadIdx.x;
  const int xcd = bid & 7;
  const int b   = xcd >> 1;                       // 2 XCDs per batch
  const int qb  = ((bid >> 3) << 1) | (xcd & 1);  // 0..127 (32 q-rows each)
  const int w = t >> 6, l4 = t & 15, lh = (t >> 4) & 3;
  const int sgrp = w >> 1, wq = w & 1;

  // LDS: 4 split-groups x (K tile 64x64 swizzled + V^T tile 64 x pitch72)
  __shared__ __align__(16) u16 kvbuf[16384 + 18432];   // 69632 B

  u16* kt_w = kvbuf + sgrp * 4096;
  u16* vt_w = kvbuf + 16384 + sgrp * 4608;

  // ---- Q fragment (registers); MFMA B operand (col = q = l4) ----
  const int qrow = qb * 32 + wq * 16 + l4;
  const u16* qp = Q + ((size_t)b * 4096 + qrow) * 64 + lh * 8;
  bf16x8 qa0 = *(const bf16x8*)qp;        // ch 0..31
  bf16x8 qa1 = *(const bf16x8*)(qp + 32); // ch 32..63

  f32x4 ot[4] = {{0,0,0,0},{0,0,0,0},{0,0,0,0},{0,0,0,0}};
  float lr = 0.f;

  // ---- staging: 128 threads per split; thread covers 64B of K row skr
  //      (half hf) and 64B of V row skr ----
  const int tl = t & 127;
  const int skr = tl >> 1, hf = tl & 1;
  const u16* kgp = K + ((size_t)b * 4096 + sgrp * 1024 + skr) * 64 + hf * 32;
  const u16* vgp = V + ((size_t)b * 64 + skr) * 4096 + sgrp * 1024 + hf * 32;
  const u32 fbw = (u32)(((skr & 3) | (((skr >> 3) & 1) << 2)) << 4);
  u16* kwp0 = kt_w + skr * 64 + ((((u32)(hf * 64))      ^ fbw) >> 1);
  u16* kwp1 = kt_w + skr * 64 + ((((u32)(hf * 64 + 16)) ^ fbw) >> 1);
  u16* kwp2 = kt_w + skr * 64 + ((((u32)(hf * 64 + 32)) ^ fbw) >> 1);
  u16* kwp3 = kt_w + skr * 64 + ((((u32)(hf * 64 + 48)) ^ fbw) >> 1);
  u16* vwp  = vt_w + skr * 72 + hf * 32;

  // ---- K-fragment LDS offsets (u16 units); permuted-row A-frag ----
  const int rbase = ((l4 >> 2) << 3) + (l4 & 3);        // 8*(l4>>2)+(l4&3)
  const int fbr   = ((l4 & 3) | (((l4 >> 2) & 1) << 2)) << 4;
  const int offL  = ((lh * 16) ^ fbr) >> 1;             // ch 0..31
  const int offH  = offL ^ 32;                          // ch 32..63

  // prefetch tile 0
  u32x4 rk0 = *(const u32x4*)kgp;
  u32x4 rk1 = *(const u32x4*)(kgp + 8);
  u32x4 rk2 = *(const u32x4*)(kgp + 16);
  u32x4 rk3 = *(const u32x4*)(kgp + 24);
  u32x4 rv0 = *(const u32x4*)vgp;
  u32x4 rv1 = *(const u32x4*)(vgp + 8);
  u32x4 rv2 = *(const u32x4*)(vgp + 16);
  u32x4 rv3 = *(const u32x4*)(vgp + 24);

  #pragma unroll 1
  for (int kti = 0; kti < 16; ++kti) {
    *(u32x4*)kwp0 = rk0;
    *(u32x4*)kwp1 = rk1;
    *(u32x4*)kwp2 = rk2;
    *(u32x4*)kwp3 = rk3;
    *(u32x4*)vwp = rv0;
    *(u32x4*)(vwp + 8)  = rv1;
    *(u32x4*)(vwp + 16) = rv2;
    *(u32x4*)(vwp + 24) = rv3;
    __syncthreads();

    if (kti < 15) {   // issue next tile early; latency hides under compute
      rk0 = *(const u32x4*)(kgp + (kti + 1) * 4096);
      rk1 = *(const u32x4*)(kgp + (kti + 1) * 4096 + 8);
      rk2 = *(const u32x4*)(kgp + (kti + 1) * 4096 + 16);
      rk3 = *(const u32x4*)(kgp + (kti + 1) * 4096 + 24);
      rv0 = *(const u32x4*)(vgp + (kti + 1) * 64);
      rv1 = *(const u32x4*)(vgp + (kti + 1) * 64 + 8);
      rv2 = *(const u32x4*)(vgp + (kti + 1) * 64 + 16);
      rv3 = *(const u32x4*)(vgp + (kti + 1) * 64 + 24);
    }

    #pragma unroll
    for (int ss = 0; ss < 2; ++ss) {
      const u16* kr0 = kt_w + (ss * 32 + rbase) * 64;       // tile0 rows
      const u16* kr1 = kr0 + 4 * 64;                        // tile1 rows (+4)
      bf16x8 vf0 = *(const bf16x8*)(vt_w + (l4)      * 72 + ss * 32 + lh * 8);
      bf16x8 vf1 = *(const bf16x8*)(vt_w + (16 + l4) * 72 + ss * 32 + lh * 8);
      bf16x8 vf2 = *(const bf16x8*)(vt_w + (32 + l4) * 72 + ss * 32 + lh * 8);
      bf16x8 vf3 = *(const bf16x8*)(vt_w + (48 + l4) * 72 + ss * 32 + lh * 8);
      bf16x8 k00 = *(const bf16x8*)(kr0 + offL);
      bf16x8 k01 = *(const bf16x8*)(kr0 + offH);
      bf16x8 k10 = *(const bf16x8*)(kr1 + offL);
      bf16x8 k11 = *(const bf16x8*)(kr1 + offH);

      f32x4 s0 = {0, 0, 0, 0}, s1 = {0, 0, 0, 0};
      s0 = __builtin_amdgcn_mfma_f32_16x16x32_bf16(k00, qa0, s0, 0, 0, 0);
      s0 = __builtin_amdgcn_mfma_f32_16x16x32_bf16(k01, qa1, s0, 0, 0, 0);
      s1 = __builtin_amdgcn_mfma_f32_16x16x32_bf16(k10, qa0, s1, 0, 0, 0);
      s1 = __builtin_amdgcn_mfma_f32_16x16x32_bf16(k11, qa1, s1, 0, 0, 0);
      // s0[r] = S[key ss*32+8lh+r][q=l4]; s1[r] = key +4

      float p0[4], p1[4];
      #pragma unroll
      for (int r = 0; r < 4; ++r) {
        p0[r] = exp2f(s0[r]);
        p1[r] = exp2f(s1[r]);
        lr += p0[r] + p1[r];
      }
      u32x4 pw;
      pw[0] = cvt_pk_bf16(p0[0], p0[1]);
      pw[1] = cvt_pk_bf16(p0[2], p0[3]);
      pw[2] = cvt_pk_bf16(p1[0], p1[1]);
      pw[3] = cvt_pk_bf16(p1[2], p1[3]);
      bf16x8 pf = __builtin_bit_cast(bf16x8, pw);   // B frag: col=q, k=8lh+j

      ot[0] = __builtin_amdgcn_mfma_f32_16x16x32_bf16(vf0, pf, ot[0], 0, 0, 0);
      ot[1] = __builtin_amdgcn_mfma_f32_16x16x32_bf16(vf1, pf, ot[1], 0, 0, 0);
      ot[2] = __builtin_amdgcn_mfma_f32_16x16x32_bf16(vf2, pf, ot[2], 0, 0, 0);
      ot[3] = __builtin_amdgcn_mfma_f32_16x16x32_bf16(vf3, pf, ot[3], 0, 0, 0);
    }
    __syncthreads();
  }

  // ---- reduce L across the 4 lh-groups (bits 4,5) ----
  lr += __shfl_xor(lr, 16, 64);
  lr += __shfl_xor(lr, 32, 64);

  // ---- write per-wave partials to LDS (overlay dead K/V region) ----
  float* opb = (float*)kvbuf;               // [8 waves][64 ch][16 q] = 32KB
  float* mlb = (float*)(kvbuf + 16384);     // [8 waves][16 q] L = 512B
  #pragma unroll
  for (int d = 0; d < 4; ++d)
    #pragma unroll
    for (int r = 0; r < 4; ++r)
      opb[w * 1024 + (16 * d + lh * 4 + r) * 16 + l4] = ot[d][r];
  if (lh == 0) mlb[w * 16 + l4] = lr;
  __syncthreads();

  // ---- merge 4 splits (plain sums), add b_out, write U^T ----
  // wave for (split s, q-subtile wq2) = 2*s + wq2
  const int ch = t >> 3, qq = t & 7;        // ch 0..63, q-quad 0..7
  const int q0 = qq * 4;
  const int wq2 = q0 >> 4, ql = q0 & 15;
  const float bout_c = bo[ch];
  f32x4 Osum = {0, 0, 0, 0};
  float Ls[4];
  #pragma unroll
  for (int j = 0; j < 4; ++j) Ls[j] = 0.f;
  #pragma unroll
  for (int s = 0; s < 4; ++s) {
    const int pw_ = 2 * s + wq2;
    f32x4 Ov = *(const f32x4*)&opb[pw_ * 1024 + ch * 16 + ql];
    #pragma unroll
    for (int j = 0; j < 4; ++j) {
      Osum[j] += Ov[j];
      Ls[j]   += mlb[pw_ * 16 + ql + j];
    }
  }
  f32x4 res;
  #pragma unroll
  for (int j = 0; j < 4; ++j) res[j] = Osum[j] / Ls[j] + bout_c;
  *(f32x4*)(Sa + ((size_t)b * 64 + ch) * 4096 + (size_t)qb * 32 + q0) = res;
}

// ---------------------------------------------------------------------------
// Kernel 3: BN batch stats over T = upsample_bilinear_ac(U, 2), recomputed
// on the fly. grid 256 = (b,c) x 1024 threads (16 waves for latency hiding).
// ---------------------------------------------------------------------------
__global__ __launch_bounds__(1024) void k_stats(const float* __restrict__ U,
                                                float* __restrict__ stats)
{
  const int c = blockIdx.x & 63, b = blockIdx.x >> 6, t = threadIdx.x;
  __shared__ __align__(16) float up[4096];
  __shared__ float red[32];
  *(f32x4*)&up[t * 4] = *(const f32x4*)(U + ((size_t)b * 64 + c) * 4096 + t * 4);
  __syncthreads();
  const float R = 0.49606299212598425f;   // 63/127 (matches f32 ref arithmetic)
  float sum = 0.f, ssq = 0.f;
  #pragma unroll 4
  for (int i = 0; i < 16; ++i) {
    int px = t + 1024 * i;
    int yo = px >> 7, xo = px & 127;
    float ys = yo * R; int y0 = (int)ys; float wy = ys - y0; int y1 = min(y0 + 1, 63);
    float xs = xo * R; int x0 = (int)xs; float wx = xs - x0; int x1 = min(x0 + 1, 63);
    const float* r0 = up + y0 * 64; const float* r1 = up + y1 * 64;
    float v0 = r0[x0] * (1.f - wx) + r0[x1] * wx;
    float v1 = r1[x0] * (1.f - wx) + r1[x1] * wx;
    float v = v0 * (1.f - wy) + v1 * wy;
    sum += v; ssq += v * v;
  }
  #pragma unroll
  for (int d = 32; d >= 1; d >>= 1) {
    sum += __shfl_down(sum, d, 64);
    ssq += __shfl_down(ssq, d, 64);
  }
  if ((t & 63) == 0) { red[t >> 6] = sum; red[16 + (t >> 6)] = ssq; }
  __syncthreads();
  if (t == 0) {
    float s = 0.f, q = 0.f;
    #pragma unroll
    for (int i = 0; i < 16; ++i) { s += red[i]; q += red[16 + i]; }
    atomicAdd(&stats[c], s);
    atomicAdd(&stats[64 + c], q);
  }
}

// ---------------------------------------------------------------------------
// Kernel 4: out = x + gamma * BN(T). grid 256 = (b,c) x 1024 threads.
// ---------------------------------------------------------------------------
__global__ __launch_bounds__(1024) void k_apply(
    const float* __restrict__ U, const float* __restrict__ stats,
    const float* __restrict__ x, const float* __restrict__ bng,
    const float* __restrict__ bnb, const float* __restrict__ gam,
    float* __restrict__ out)
{
  const int c = blockIdx.x & 63, b = blockIdx.x >> 6, t = threadIdx.x;
  __shared__ __align__(16) float up[4096];
  *(f32x4*)&up[t * 4] = *(const f32x4*)(U + ((size_t)b * 64 + c) * 4096 + t * 4);
  __syncthreads();
  const float inv = 1.0f / 65536.0f;      // B*H*W
  float mean = stats[c] * inv;
  float var  = stats[64 + c] * inv - mean * mean;
  float rsig = rsqrtf(var + 1e-5f);
  float g = gam[0];
  float A  = g * bng[c] * rsig;
  float Bc = g * (bnb[c] - mean * rsig * bng[c]);
  const float R = 0.49606299212598425f;
  const size_t base = ((size_t)b * 64 + c) * 16384;
  #pragma unroll 4
  for (int i = 0; i < 16; ++i) {
    int px = t + 1024 * i;
    int yo = px >> 7, xo = px & 127;
    float ys = yo * R; int y0 = (int)ys; float wy = ys - y0; int y1 = min(y0 + 1, 63);
    float xs = xo * R; int x0 = (int)xs; float wx = xs - x0; int x1 = min(x0 + 1, 63);
    const float* r0 = up + y0 * 64; const float* r1 = up + y1 * 64;
    float v0 = r0[x0] * (1.f - wx) + r0[x1] * wx;
    float v1 = r1[x0] * (1.f - wx) + r1[x1] * wx;
    float v = v0 * (1.f - wy) + v1 * wy;
    out[base + px] = x[base + px] + v * A + Bc;
  }
}

// ---------------------------------------------------------------------------
extern "C" void kernel_launch(void* const* d_in, const int* in_sizes, int n_in,
                              void* d_out, int out_size, void* d_ws, size_t ws_size,
                              hipStream_t stream)
{
  const float* x      = (const float*)d_in[0];
  const float* memory = (const float*)d_in[1];
  const float* Wqkv   = (const float*)d_in[2];
  const float* bqkv   = (const float*)d_in[3];
  const float* Wout   = (const float*)d_in[4];
  const float* bout   = (const float*)d_in[5];
  const float* bng    = (const float*)d_in[6];
  const float* bnb    = (const float*)d_in[7];
  const float* gamma  = (const float*)d_in[8];

  char* ws = (char*)d_ws;
  u16*   Q     = (u16*)(ws + 0);              // 2 MB
  u16*   Kk    = (u16*)(ws + (2u << 20));     // 2 MB
  u16*   Vt    = (u16*)(ws + (4u << 20));     // 2 MB  (V' = Wout @ V^T)
  float* U     = (float*)(ws + (10u << 20));  // 4 MB
  float* stats = (float*)(ws + (14u << 20));  // 512 B
  float* out   = (float*)d_out;

  k_qkvpool<<<dim3(64, 4), 512, 0, stream>>>(memory, Wqkv, bqkv, Wout, Q, Kk, Vt, stats);
  k_attn   <<<512, 512, 0, stream>>>(Q, Kk, Vt, bout, U);
  k_stats  <<<256, 1024, 0, stream>>>(U, stats);
  k_apply  <<<256, 1024, 0, stream>>>(U, stats, x, bng, bnb, gamma, out);
}

// Round 12
// 61.118 us; speedup vs baseline: 1.1623x; 1.1623x over previous
//
#include <hip/hip_runtime.h>
#include <stdint.h>

typedef unsigned short u16;
typedef unsigned int   u32;
typedef __attribute__((ext_vector_type(8))) __bf16 bf16x8;
typedef __attribute__((ext_vector_type(4))) float  f32x4;
typedef __attribute__((ext_vector_type(2))) float  f32x2;
typedef __attribute__((ext_vector_type(4))) u32    u32x4;
typedef __attribute__((ext_vector_type(2))) u32    u32x2;

#define QSCALE 0.18033688011112042f   // log2(e) / sqrt(64)

__device__ __forceinline__ u16 f2bf(float x) {
  u32 u = __builtin_bit_cast(u32, x);
  u = (u + 0x7FFFu + ((u >> 16) & 1u)) >> 16;
  return (u16)u;
}

__device__ __forceinline__ u32 cvt_pk_bf16(float lo, float hi) {
  u32 r;
  asm("v_cvt_pk_bf16_f32 %0, %1, %2" : "=v"(r) : "v"(lo), "v"(hi));
  return r;
}

// ---------------------------------------------------------------------------
// Kernel 1: qkv = maxpool2(conv1x1(memory, W_qkv)) + b_qkv  — MFMA, 8 waves.
// ALSO folds W_out into V:  V' = W_out @ V^T  (64x64 GEMM on block-local V).
// outputs: Q [4][4096][64] bf16 (pre-scaled), K [4][4096][64] bf16,
//          V' [4][64][4096] bf16. Also zeroes the BN stats buffer.
// grid (64 oy, 4 b) x 512 threads      [round-6 verified version]
// ---------------------------------------------------------------------------
__global__ __launch_bounds__(512) void k_qkvpool(
    const float* __restrict__ mem, const float* __restrict__ Wqkv,
    const float* __restrict__ bqkv, const float* __restrict__ Wout,
    u16* __restrict__ Q, u16* __restrict__ K, u16* __restrict__ V,
    float* __restrict__ stats)
{
  const int oy = blockIdx.x, b = blockIdx.y, t = threadIdx.x;
  const int w = t >> 6, l4 = t & 15, lh = (t >> 4) & 3;
  const int wq = w & 3, wp = w >> 2;

  if (oy == 0 && b == 0 && t < 128) stats[t] = 0.f;

  __shared__ __align__(16) u16 lds[49152];      // 96 KB
  u16* mlds  = lds;           // [px 0..255][c] bf16, XOR-swizzled rows
  u16* wlds  = lds + 16384;   // [oc 0..191][c] bf16, swizzled
  u16* qlds  = lds + 28672;   // [ox][oc]
  u16* klds  = lds + 32768;   // [ox][oc-64]
  u16* vldsT = lds + 36864;   // [ox][vch] bf16, swizzled  (GEMM B operand)
  u16* wolds = lds + 40960;   // [oc 0..63][c] W_out bf16, swizzled
  u16* vplds = lds + 45056;   // [oc][ox]  V' output

  float bias[3][4];
  #pragma unroll
  for (int j = 0; j < 3; ++j)
    #pragma unroll
    for (int r = 0; r < 4; ++r) {
      int oc = wq * 48 + 16 * j + lh * 4 + r;
      float bv = bqkv[oc];
      bias[j][r] = (oc < 64) ? bv * QSCALE : bv;
    }

  { // stage mem rows (2oy, 2oy+1) -> bf16 LDS [px][c], swizzled
    const float* src = mem + ((size_t)b * 64) * 16384 + 2 * oy * 128;
    #pragma unroll
    for (int i = 0; i < 8; ++i) {
      int g = t + 512 * i;                 // 4-channel pack id, 0..4095
      int px = g & 255, c0 = (g >> 8) * 4;
      float f0 = src[(size_t)(c0 + 0) * 16384 + px];
      float f1 = src[(size_t)(c0 + 1) * 16384 + px];
      float f2 = src[(size_t)(c0 + 2) * 16384 + px];
      float f3 = src[(size_t)(c0 + 3) * 16384 + px];
      u32x2 pk;
      pk[0] = (u32)f2bf(f0) | ((u32)f2bf(f1) << 16);
      pk[1] = (u32)f2bf(f2) | ((u32)f2bf(f3) << 16);
      *(u32x2*)(mlds + px * 64 + (((c0 * 2) ^ ((px & 7) << 4)) >> 1)) = pk;
    }
  }
  { // stage W_qkv -> bf16 LDS [oc][c], swizzled
    #pragma unroll
    for (int i = 0; i < 6; ++i) {
      int g = t + 512 * i;                 // 0..3071
      int oc = g >> 4, c0 = (g & 15) * 4;
      f32x4 wv = *(const f32x4*)(Wqkv + oc * 64 + c0);
      u32x2 pk;
      pk[0] = (u32)f2bf(wv[0]) | ((u32)f2bf(wv[1]) << 16);
      pk[1] = (u32)f2bf(wv[2]) | ((u32)f2bf(wv[3]) << 16);
      *(u32x2*)(wlds + oc * 64 + (((c0 * 2) ^ ((oc & 7) << 4)) >> 1)) = pk;
    }
  }
  { // stage W_out -> bf16 LDS [oc][c], swizzled
    #pragma unroll
    for (int i = 0; i < 2; ++i) {
      int g = t + 512 * i;                 // 0..1023
      int oc = g >> 4, c0 = (g & 15) * 4;
      f32x4 wv = *(const f32x4*)(Wout + oc * 64 + c0);
      u32x2 pk;
      pk[0] = (u32)f2bf(wv[0]) | ((u32)f2bf(wv[1]) << 16);
      pk[1] = (u32)f2bf(wv[2]) | ((u32)f2bf(wv[3]) << 16);
      *(u32x2*)(wolds + oc * 64 + (((c0 * 2) ^ ((oc & 7) << 4)) >> 1)) = pk;
    }
  }
  __syncthreads();

  const int sw  = (l4 & 7) << 4;
  const int oF0 = ((lh * 16) ^ sw) >> 1;
  const int oF1 = ((64 + lh * 16) ^ sw) >> 1;
  bf16x8 af[3][2];
  #pragma unroll
  for (int j = 0; j < 3; ++j) {
    const u16* ar = wlds + (wq * 48 + 16 * j + l4) * 64;
    af[j][0] = *(const bf16x8*)(ar + oF0);
    af[j][1] = *(const bf16x8*)(ar + oF1);
  }

  // ---- main conv+pool loop: each wave handles 4 px-tile-pairs ----
  #pragma unroll 2
  for (int tpi = 0; tpi < 4; ++tpi) {
    const int tp = wp * 4 + tpi;
    const u16* br0 = mlds + (16 * tp + l4) * 64;
    const u16* br1 = mlds + (128 + 16 * tp + l4) * 64;
    bf16x8 b00 = *(const bf16x8*)(br0 + oF0);
    bf16x8 b01 = *(const bf16x8*)(br0 + oF1);
    bf16x8 b10 = *(const bf16x8*)(br1 + oF0);
    bf16x8 b11 = *(const bf16x8*)(br1 + oF1);
    const int ox = 8 * tp + (l4 >> 1);
    #pragma unroll
    for (int j = 0; j < 3; ++j) {
      f32x4 a0 = {0, 0, 0, 0}, a1 = {0, 0, 0, 0};
      a0 = __builtin_amdgcn_mfma_f32_16x16x32_bf16(af[j][0], b00, a0, 0, 0, 0);
      a0 = __builtin_amdgcn_mfma_f32_16x16x32_bf16(af[j][1], b01, a0, 0, 0, 0);
      a1 = __builtin_amdgcn_mfma_f32_16x16x32_bf16(af[j][0], b10, a1, 0, 0, 0);
      a1 = __builtin_amdgcn_mfma_f32_16x16x32_bf16(af[j][1], b11, a1, 0, 0, 0);
      const int ocj = wq * 48 + 16 * j;
      const float sc = (ocj < 64) ? QSCALE : 1.0f;
      #pragma unroll
      for (int r = 0; r < 4; ++r) {
        float m = fmaxf(a0[r], a1[r]);             // pool across rows
        m = fmaxf(m, __shfl_xor(m, 1, 64));        // pool across x pair
        u16 val = f2bf(m * sc + bias[j][r]);
        if ((l4 & 1) == 0) {
          int oc = ocj + lh * 4 + r;
          if (ocj < 64)       qlds[ox * 64 + oc]        = val;
          else if (ocj < 128) klds[ox * 64 + (oc - 64)] = val;
          else {
            int vch = oc - 128;   // [ox][vch], swizzled for GEMM B reads
            vldsT[ox * 64 + (((vch * 2) ^ ((ox & 7) << 4)) >> 1)] = val;
          }
        }
      }
    }
  }
  __syncthreads();

  // ---- V' = W_out @ V^T  (8 waves: oc-tile = wq*16, px-half = wp) ----
  {
    const u16* ar = wolds + (wq * 16 + l4) * 64;
    bf16x8 aw0 = *(const bf16x8*)(ar + oF0);
    bf16x8 aw1 = *(const bf16x8*)(ar + oF1);
    #pragma unroll
    for (int nti = 0; nti < 2; ++nti) {
      const int nt = wp * 2 + nti;
      const u16* brow = vldsT + (nt * 16 + l4) * 64;
      bf16x8 bw0 = *(const bf16x8*)(brow + oF0);
      bf16x8 bw1 = *(const bf16x8*)(brow + oF1);
      f32x4 u = {0, 0, 0, 0};
      u = __builtin_amdgcn_mfma_f32_16x16x32_bf16(aw0, bw0, u, 0, 0, 0);
      u = __builtin_amdgcn_mfma_f32_16x16x32_bf16(aw1, bw1, u, 0, 0, 0);
      #pragma unroll
      for (int r = 0; r < 4; ++r) {
        int oc = wq * 16 + lh * 4 + r;
        vplds[oc * 64 + nt * 16 + l4] = f2bf(u[r]);
      }
    }
  }
  __syncthreads();

  // ---- coalesced 16B copy-out ----
  {
    int r = t >> 3, e8 = (t & 7) * 8;
    size_t nb = (size_t)oy * 64;
    *(u32x4*)(Q + ((size_t)b * 4096 + nb + r) * 64 + e8) = *(const u32x4*)(qlds + r * 64 + e8);
    *(u32x4*)(K + ((size_t)b * 4096 + nb + r) * 64 + e8) = *(const u32x4*)(klds + r * 64 + e8);
    *(u32x4*)(V + ((size_t)b * 64 + r) * 4096 + nb + e8) = *(const u32x4*)(vplds + r * 64 + e8);
  }
}

// ---------------------------------------------------------------------------
// Kernel 2: flash attention — ROUND-6 VERIFIED BEST (61.7 µs total config).
// 16 waves = 4 key-splits x 4 q-subtiles, swapped QK^T, P in registers,
// no-max softmax, single-buffer staging with 1-deep prefetch.
// V is pre-multiplied by W_out: output IS U = W_out(PV)/L + b_out.
// grid (64 qb, 4 b) x 1024 threads
// ---------------------------------------------------------------------------
__global__ __launch_bounds__(1024, 4) void k_attn(
    const u16* __restrict__ Q, const u16* __restrict__ K,
    const u16* __restrict__ V, const float* __restrict__ bo,
    float* __restrict__ Sa)
{
  const int qb = blockIdx.x, b = blockIdx.y, t = threadIdx.x;
  const int w = t >> 6, l4 = t & 15, lh = (t >> 4) & 3;
  const int sgrp = w >> 2, wq = w & 3;

  // LDS: 4 split-groups x (K tile 64x64 swizzled + V^T tile 64 x pitch72)
  __shared__ __align__(16) u16 kvbuf[16384 + 18432];   // 32KB K + 36KB V

  u16* kt_w = kvbuf + sgrp * 4096;
  u16* vt_w = kvbuf + 16384 + sgrp * 4608;

  // ---- Q fragment (registers); MFMA B operand (col = q = l4) ----
  const int qrow = qb * 64 + wq * 16 + l4;
  const u16* qp = Q + ((size_t)b * 4096 + qrow) * 64 + lh * 8;
  bf16x8 qa0 = *(const bf16x8*)qp;        // ch 0..31
  bf16x8 qa1 = *(const bf16x8*)(qp + 32); // ch 32..63

  f32x4 ot[4] = {{0,0,0,0},{0,0,0,0},{0,0,0,0},{0,0,0,0}};
  float lr = 0.f;

  // ---- staging addresses (group sgrp stages its own 64-key tile) ----
  const int tl = t & 255;
  const int skr = tl >> 2, skc = tl & 3;  // row 0..63, 2x16B chunks
  const u16* kgp = K + ((size_t)b * 4096 + sgrp * 1024 + skr) * 64 + skc * 16;
  const u16* vgp = V + ((size_t)b * 64 + skr) * 4096 + sgrp * 1024 + skc * 16;
  const u32 fbw = (u32)(((skr & 3) | (((skr >> 3) & 1) << 2)) << 4);
  u16* kwp0 = kt_w + skr * 64 + ((((u32)(skc * 32))      ^ fbw) >> 1);
  u16* kwp1 = kt_w + skr * 64 + ((((u32)(skc * 32 + 16)) ^ fbw) >> 1);
  u16* vwp  = vt_w + skr * 72 + skc * 16;

  // ---- K-fragment LDS offsets (u16 units); permuted-row A-frag ----
  const int rbase = ((l4 >> 2) << 3) + (l4 & 3);        // 8*(l4>>2)+(l4&3)
  const int fbr   = ((l4 & 3) | (((l4 >> 2) & 1) << 2)) << 4;
  const int offL  = ((lh * 16) ^ fbr) >> 1;             // ch 0..31
  const int offH  = offL ^ 32;                          // ch 32..63

  // prefetch tile 0
  u32x4 rk0 = *(const u32x4*)kgp;
  u32x4 rk1 = *(const u32x4*)(kgp + 8);
  u32x4 rv0 = *(const u32x4*)vgp;
  u32x4 rv1 = *(const u32x4*)(vgp + 8);

  #pragma unroll 1
  for (int kti = 0; kti < 16; ++kti) {
    *(u32x4*)kwp0 = rk0;
    *(u32x4*)kwp1 = rk1;
    *(u32x4*)vwp = rv0;
    *(u32x4*)(vwp + 8) = rv1;
    __syncthreads();

    if (kti < 15) {   // issue next tile early; latency hides under compute
      rk0 = *(const u32x4*)(kgp + (kti + 1) * 4096);
      rk1 = *(const u32x4*)(kgp + (kti + 1) * 4096 + 8);
      rv0 = *(const u32x4*)(vgp + (kti + 1) * 64);
      rv1 = *(const u32x4*)(vgp + (kti + 1) * 64 + 8);
    }

    #pragma unroll
    for (int ss = 0; ss < 2; ++ss) {
      const u16* kr0 = kt_w + (ss * 32 + rbase) * 64;       // tile0 rows
      const u16* kr1 = kr0 + 4 * 64;                        // tile1 rows (+4)
      // V-frags first (independent of S) — overlap with QK MFMAs
      bf16x8 vf0 = *(const bf16x8*)(vt_w + (l4)      * 72 + ss * 32 + lh * 8);
      bf16x8 vf1 = *(const bf16x8*)(vt_w + (16 + l4) * 72 + ss * 32 + lh * 8);
      bf16x8 vf2 = *(const bf16x8*)(vt_w + (32 + l4) * 72 + ss * 32 + lh * 8);
      bf16x8 vf3 = *(const bf16x8*)(vt_w + (48 + l4) * 72 + ss * 32 + lh * 8);
      bf16x8 k00 = *(const bf16x8*)(kr0 + offL);
      bf16x8 k01 = *(const bf16x8*)(kr0 + offH);
      bf16x8 k10 = *(const bf16x8*)(kr1 + offL);
      bf16x8 k11 = *(const bf16x8*)(kr1 + offH);

      f32x4 s0 = {0, 0, 0, 0}, s1 = {0, 0, 0, 0};
      s0 = __builtin_amdgcn_mfma_f32_16x16x32_bf16(k00, qa0, s0, 0, 0, 0);
      s0 = __builtin_amdgcn_mfma_f32_16x16x32_bf16(k01, qa1, s0, 0, 0, 0);
      s1 = __builtin_amdgcn_mfma_f32_16x16x32_bf16(k10, qa0, s1, 0, 0, 0);
      s1 = __builtin_amdgcn_mfma_f32_16x16x32_bf16(k11, qa1, s1, 0, 0, 0);
      // s0[r] = S[key ss*32+8lh+r][q=l4]; s1[r] = key +4

      float p0[4], p1[4];
      #pragma unroll
      for (int r = 0; r < 4; ++r) {
        p0[r] = exp2f(s0[r]);
        p1[r] = exp2f(s1[r]);
        lr += p0[r] + p1[r];
      }
      u32x4 pw;
      pw[0] = cvt_pk_bf16(p0[0], p0[1]);
      pw[1] = cvt_pk_bf16(p0[2], p0[3]);
      pw[2] = cvt_pk_bf16(p1[0], p1[1]);
      pw[3] = cvt_pk_bf16(p1[2], p1[3]);
      bf16x8 pf = __builtin_bit_cast(bf16x8, pw);   // B frag: col=q=l4, k=8lh+j

      ot[0] = __builtin_amdgcn_mfma_f32_16x16x32_bf16(vf0, pf, ot[0], 0, 0, 0);
      ot[1] = __builtin_amdgcn_mfma_f32_16x16x32_bf16(vf1, pf, ot[1], 0, 0, 0);
      ot[2] = __builtin_amdgcn_mfma_f32_16x16x32_bf16(vf2, pf, ot[2], 0, 0, 0);
      ot[3] = __builtin_amdgcn_mfma_f32_16x16x32_bf16(vf3, pf, ot[3], 0, 0, 0);
    }
    __syncthreads();
  }

  // ---- reduce L across the 4 lh-groups (bits 4,5) ----
  lr += __shfl_xor(lr, 16, 64);
  lr += __shfl_xor(lr, 32, 64);

  // ---- write per-wave partials to LDS (overlay dead K/V region) ----
  float* opb = (float*)kvbuf;             // [16 waves][64 ch][16 q] = 64KB
  float* mlb = (float*)(kvbuf + 32768);   // [16 waves][16 q] L = 1KB
  #pragma unroll
  for (int d = 0; d < 4; ++d)
    #pragma unroll
    for (int r = 0; r < 4; ++r)
      opb[w * 1024 + (16 * d + lh * 4 + r) * 16 + l4] = ot[d][r];
  if (lh == 0) mlb[w * 16 + l4] = lr;
  __syncthreads();

  // ---- merge 4 splits (plain sums), add b_out, write U^T ----
  const int ch = t >> 4, q0v = (t & 15) * 4;
  const float bout_c = bo[ch];
  f32x4 res;
  #pragma unroll
  for (int j = 0; j < 4; ++j) {
    int q = q0v + j, wq2 = q >> 4, ql = q & 15;
    float L = mlb[(wq2)*16      + ql] + mlb[(4 + wq2)*16  + ql]
            + mlb[(8 + wq2)*16  + ql] + mlb[(12 + wq2)*16 + ql];
    float O = opb[(wq2)*1024      + ch * 16 + ql]
            + opb[(4 + wq2)*1024  + ch * 16 + ql]
            + opb[(8 + wq2)*1024  + ch * 16 + ql]
            + opb[(12 + wq2)*1024 + ch * 16 + ql];
    res[j] = O / L + bout_c;
  }
  *(f32x4*)(Sa + ((size_t)b * 64 + ch) * 4096 + (size_t)qb * 64 + q0v) = res;
}

// ---------------------------------------------------------------------------
// Kernel 3: BN batch stats over T = upsample_bilinear_ac(U, 2), recomputed
// on the fly. grid 256 = (b,c) x 1024 threads. VECTORIZED: each thread does
// 4 consecutive x-pixels (shared y-interp), 4 iterations.
// ---------------------------------------------------------------------------
__global__ __launch_bounds__(1024) void k_stats(const float* __restrict__ U,
                                                float* __restrict__ stats)
{
  const int c = blockIdx.x & 63, b = blockIdx.x >> 6, t = threadIdx.x;
  __shared__ __align__(16) float up[4096];
  __shared__ float red[32];
  *(f32x4*)&up[t * 4] = *(const f32x4*)(U + ((size_t)b * 64 + c) * 4096 + t * 4);
  __syncthreads();
  const float R = 0.49606299212598425f;   // 63/127 (matches f32 ref arithmetic)
  float sum = 0.f, ssq = 0.f;
  #pragma unroll
  for (int i = 0; i < 4; ++i) {
    const int px0 = i * 4096 + t * 4;        // 4 consecutive px, same row
    const int yo = px0 >> 7, xo0 = px0 & 127;
    float ys = yo * R; int y0 = (int)ys; float wy = ys - y0;
    int y1 = min(y0 + 1, 63);
    const float* r0 = up + y0 * 64; const float* r1 = up + y1 * 64;
    #pragma unroll
    for (int j = 0; j < 4; ++j) {
      int xo = xo0 + j;
      float xs = xo * R; int x0 = (int)xs; float wx = xs - x0;
      int x1 = min(x0 + 1, 63);
      float v0 = r0[x0] * (1.f - wx) + r0[x1] * wx;
      float v1 = r1[x0] * (1.f - wx) + r1[x1] * wx;
      float v = v0 * (1.f - wy) + v1 * wy;
      sum += v; ssq += v * v;
    }
  }
  #pragma unroll
  for (int d = 32; d >= 1; d >>= 1) {
    sum += __shfl_down(sum, d, 64);
    ssq += __shfl_down(ssq, d, 64);
  }
  if ((t & 63) == 0) { red[t >> 6] = sum; red[16 + (t >> 6)] = ssq; }
  __syncthreads();
  if (t == 0) {
    float s = 0.f, q = 0.f;
    #pragma unroll
    for (int i = 0; i < 16; ++i) { s += red[i]; q += red[16 + i]; }
    atomicAdd(&stats[c], s);
    atomicAdd(&stats[64 + c], q);
  }
}

// ---------------------------------------------------------------------------
// Kernel 4: out = x + gamma * BN(T). grid 256 = (b,c) x 1024 threads.
// VECTORIZED: 4 consecutive x-pixels per thread -> f32x4 16B load/store.
// ---------------------------------------------------------------------------
__global__ __launch_bounds__(1024) void k_apply(
    const float* __restrict__ U, const float* __restrict__ stats,
    const float* __restrict__ x, const float* __restrict__ bng,
    const float* __restrict__ bnb, const float* __restrict__ gam,
    float* __restrict__ out)
{
  const int c = blockIdx.x & 63, b = blockIdx.x >> 6, t = threadIdx.x;
  __shared__ __align__(16) float up[4096];
  *(f32x4*)&up[t * 4] = *(const f32x4*)(U + ((size_t)b * 64 + c) * 4096 + t * 4);
  __syncthreads();
  const float inv = 1.0f / 65536.0f;      // B*H*W
  float mean = stats[c] * inv;
  float var  = stats[64 + c] * inv - mean * mean;
  float rsig = rsqrtf(var + 1e-5f);
  float g = gam[0];
  float A  = g * bng[c] * rsig;
  float Bc = g * (bnb[c] - mean * rsig * bng[c]);
  const float R = 0.49606299212598425f;
  const size_t base = ((size_t)b * 64 + c) * 16384;
  #pragma unroll
  for (int i = 0; i < 4; ++i) {
    const int px0 = i * 4096 + t * 4;        // 4 consecutive px, same row
    const int yo = px0 >> 7, xo0 = px0 & 127;
    float ys = yo * R; int y0 = (int)ys; float wy = ys - y0;
    int y1 = min(y0 + 1, 63);
    const float* r0 = up + y0 * 64; const float* r1 = up + y1 * 64;
    f32x4 xv = *(const f32x4*)(x + base + px0);
    f32x4 ov;
    #pragma unroll
    for (int j = 0; j < 4; ++j) {
      int xo = xo0 + j;
      float xs = xo * R; int x0 = (int)xs; float wx = xs - x0;
      int x1 = min(x0 + 1, 63);
      float v0 = r0[x0] * (1.f - wx) + r0[x1] * wx;
      float v1 = r1[x0] * (1.f - wx) + r1[x1] * wx;
      float v = v0 * (1.f - wy) + v1 * wy;
      ov[j] = xv[j] + v * A + Bc;
    }
    *(f32x4*)(out + base + px0) = ov;
  }
}

// ---------------------------------------------------------------------------
extern "C" void kernel_launch(void* const* d_in, const int* in_sizes, int n_in,
                              void* d_out, int out_size, void* d_ws, size_t ws_size,
                              hipStream_t stream)
{
  const float* x      = (const float*)d_in[0];
  const float* memory = (const float*)d_in[1];
  const float* Wqkv   = (const float*)d_in[2];
  const float* bqkv   = (const float*)d_in[3];
  const float* Wout   = (const float*)d_in[4];
  const float* bout   = (const float*)d_in[5];
  const float* bng    = (const float*)d_in[6];
  const float* bnb    = (const float*)d_in[7];
  const float* gamma  = (const float*)d_in[8];

  char* ws = (char*)d_ws;
  u16*   Q     = (u16*)(ws + 0);              // 2 MB
  u16*   Kk    = (u16*)(ws + (2u << 20));     // 2 MB
  u16*   Vt    = (u16*)(ws + (4u << 20));     // 2 MB  (V' = Wout @ V^T)
  float* U     = (float*)(ws + (10u << 20));  // 4 MB
  float* stats = (float*)(ws + (14u << 20));  // 512 B
  float* out   = (float*)d_out;

  k_qkvpool<<<dim3(64, 4), 512, 0, stream>>>(memory, Wqkv, bqkv, Wout, Q, Kk, Vt, stats);
  k_attn   <<<dim3(64, 4), 1024, 0, stream>>>(Q, Kk, Vt, bout, U);
  k_stats  <<<256, 1024, 0, stream>>>(U, stats);
  k_apply  <<<256, 1024, 0, stream>>>(U, stats, x, bng, bnb, gamma, out);
}